// Round 16
// baseline (186.569 us; speedup 1.0000x reference)
//
#include <hip/hip_runtime.h>
#include <math.h>
#include <stdint.h>

#define NB 16384
#define NG 10000
#define NGT 313           // ceil(NG/32) g-tiles of 32; tail rows NaN-poisoned
#define NCH 8             // g-chunks; chunk c covers tiles [NGT*c/NCH, NGT*(c+1)/NCH)
#define MAXTPC 40         // max tiles per chunk -> 40 KiB LDS -> 4 blocks/CU

typedef _Float16 half8 __attribute__((ext_vector_type(8)));
typedef float    floatx16 __attribute__((ext_vector_type(16)));

// C/D row map for 32x32x16: row = (r&3) + 8*(r>>2) + 4*kh  (g_local here)
#define ROWMAP(r, kh) (((r) & 3) + 8 * ((r) >> 2) + 4 * (kh))

// ---- stage chunk tiles [t0, t0+nt) into LDS, computing SH rows directly from gv ----
// row g >= NG -> all-NaN (loses every ordered compare and v_max -> never wins argmax)
__device__ inline void stage_sh(const float* __restrict__ gv, half8* lds, int t0, int nt) {
    const int nrows = nt * 32;
    for (int lr = threadIdx.x; lr < nrows; lr += 256) {
        int g = t0 * 32 + lr;
        half8 h0, h1;
        if (g >= NG) {
            const _Float16 qn = (_Float16)__builtin_nanf("");
#pragma unroll
            for (int i = 0; i < 8; ++i) { h0[i] = qn; h1[i] = qn; }
        } else {
            float x = gv[3 * g + 0], y = gv[3 * g + 1], z = gv[3 * g + 2];
            float n = sqrtf(x * x + y * y + z * z);
            float dn = fmaxf(n, 1e-12f);
            float vx = x / dn, vy = y / dn, vz = z / dn;
            float x2 = vx * vx, y2 = vy * vy, z2 = vz * vz;
            const float c_m4 = (float)(0.75 * sqrt(35.0 / M_PI));
            const float c_m3 = (float)(0.75 * sqrt(35.0 / (2.0 * M_PI)));
            const float c_m2 = (float)(0.75 * sqrt(5.0 / M_PI));
            const float c_m1 = (float)(0.75 * sqrt(5.0 / (2.0 * M_PI)));
            const float c_0  = (float)((3.0 / 16.0) * sqrt(1.0 / M_PI));
            const float c_p2 = (float)((3.0 / 8.0) * sqrt(5.0 / M_PI));
            const float c_p4 = (float)((3.0 / 16.0) * sqrt(35.0 / M_PI));
            h0[0] = (_Float16)(c_m4 * vx * vy * (x2 - y2));
            h0[1] = (_Float16)(c_m3 * vy * vz * (3.0f * x2 - y2));
            h0[2] = (_Float16)(c_m2 * vx * vy * (7.0f * z2 - 1.0f));
            h0[3] = (_Float16)(c_m1 * vy * vz * (7.0f * z2 - 3.0f));
            h0[4] = (_Float16)(c_0  * (35.0f * z2 * z2 - 30.0f * z2 + 3.0f));
            h0[5] = (_Float16)(c_m1 * vx * vz * (7.0f * z2 - 3.0f));
            h0[6] = (_Float16)(c_p2 * (x2 - y2) * (7.0f * z2 - 1.0f));
            h0[7] = (_Float16)(c_m3 * vx * vz * (x2 - y2));
            h1 = (half8){0, 0, 0, 0, 0, 0, 0, 0};
            h1[0] = (_Float16)(c_p4 * (x2 * x2 - 6.0f * x2 * y2 + y2 * y2));  // k=8
            h1[1] = (_Float16)x;   // k=9..11: raw grid vec
            h1[2] = (_Float16)y;
            h1[3] = (_Float16)z;
        }
        lds[lr * 2 + 0] = h0;
        lds[lr * 2 + 1] = h1;
    }
}

// B-operand frag (f4 for one b column): B[k][col]: col=lane&31, k=(lane>>5)*8+j.
__device__ inline half8 make_bfrag(const float* __restrict__ f4, int b, int kh) {
    half8 a = {0, 0, 0, 0, 0, 0, 0, 0};
    const float* fr = f4 + (size_t)b * 9;
    if (kh == 0) {
#pragma unroll
        for (int j = 0; j < 8; ++j) a[j] = (_Float16)fr[j];
    } else {
        a[0] = (_Float16)fr[8];      // k=8
    }
    return a;
}

// merge (v2,g2) into (v,g) with numpy first-max semantics
__device__ inline void merge_vg(float& v, int& g, float v2, int g2) {
    bool take = (v2 > v) || (v2 == v && g2 < g);
    v = take ? v2 : v;
    g = take ? g2 : g;
}

// ---------------- Kernel 1: pass-1 argmax (pack fused into staging, asm select) ----------------
__global__ __launch_bounds__(256, 2) void k_pass1(const float* __restrict__ f4,
                                                  const float* __restrict__ gv,
                                                  float* __restrict__ Pv,
                                                  int* __restrict__ Pi,
                                                  int* __restrict__ cnt) {
    __shared__ half8 lds[MAXTPC * 64];      // 40 KiB
    const int lane = threadIdx.x & 63;
    const int w = threadIdx.x >> 6;
    const int W = blockIdx.x * 4 + w;       // b-tile; b = 32W .. 32W+31
    const int n = lane & 31, kh = lane >> 5;
    const int chunk = blockIdx.y;
    const int b = W * 32 + n;

    const int t0 = (NGT * chunk) / NCH;
    const int t1 = (NGT * (chunk + 1)) / NCH;
    const int nt = t1 - t0;

    stage_sh(gv, lds, t0, nt);
    // zero the pass-2 completion counters (poisoned 0xAA by harness); kernel
    // boundary orders this before pass2 reads them.
    if (chunk == 0 && threadIdx.x == 0) cnt[blockIdx.x] = 0;

    const half8 bf = make_bfrag(f4, b, kh);
    __syncthreads();

    float bv[16]; int bt[16];
#pragma unroll
    for (int r = 0; r < 16; ++r) { bv[r] = -INFINITY; bt[r] = 0; }

    const floatx16 zero16 = {0.f,0.f,0.f,0.f, 0.f,0.f,0.f,0.f, 0.f,0.f,0.f,0.f, 0.f,0.f,0.f,0.f};
    const half8* lp = &lds[n * 2 + kh];

    half8 af = *lp; lp += 64;
#pragma unroll 2
    for (int t = 0; t < nt - 1; ++t) {
        half8 afn = *lp; lp += 64;
        floatx16 c = __builtin_amdgcn_mfma_f32_32x32x16_f16(af, bf, zero16, 0, 0, 0);
        int tv = t;
#pragma unroll
        for (int r = 0; r < 16; ++r) {
            float cr = c[r];
            asm("v_cmp_gt_f32 vcc, %2, %0\n\t"
                "v_cndmask_b32 %1, %1, %3, vcc\n\t"
                "v_max_f32 %0, %0, %2"
                : "+v"(bv[r]), "+v"(bt[r])
                : "v"(cr), "v"(tv)
                : "vcc");
        }
        af = afn;
    }
    {
        floatx16 c = __builtin_amdgcn_mfma_f32_32x32x16_f16(af, bf, zero16, 0, 0, 0);
        int tv = nt - 1;
#pragma unroll
        for (int r = 0; r < 16; ++r) {
            float cr = c[r];
            asm("v_cmp_gt_f32 vcc, %2, %0\n\t"
                "v_cndmask_b32 %1, %1, %3, vcc\n\t"
                "v_max_f32 %0, %0, %2"
                : "+v"(bv[r]), "+v"(bt[r])
                : "v"(cr), "v"(tv)
                : "vcc");
        }
    }
    float v = bv[0]; int g = ((t0 + bt[0]) << 5) + ROWMAP(0, kh);
#pragma unroll
    for (int r = 1; r < 16; ++r)
        merge_vg(v, g, bv[r], ((t0 + bt[r]) << 5) + ROWMAP(r, kh));
    merge_vg(v, g, __shfl_xor(v, 32), __shfl_xor(g, 32));
    if (kh == 0) {
        Pv[(size_t)chunk * NB + b] = v;
        Pi[(size_t)chunk * NB + b] = g;
    }
}

// ---------------- Kernel 2: pass-2 masked argmax + fused finalize (last-block ticket) ----------------
__global__ __launch_bounds__(256, 2) void k_pass2(const float* __restrict__ f0,
                                                  const float* __restrict__ f4,
                                                  const float* __restrict__ gv,
                                                  const float* __restrict__ P1v,
                                                  const int* __restrict__ P1i,
                                                  float* __restrict__ P2v,
                                                  int* __restrict__ P2i,
                                                  int* __restrict__ cnt,
                                                  float* __restrict__ out) {
    __shared__ half8 lds[MAXTPC * 64];
    __shared__ int s_ticket;
    const int lane = threadIdx.x & 63;
    const int w = threadIdx.x >> 6;
    const int W = blockIdx.x * 4 + w;
    const int n = lane & 31, kh = lane >> 5;
    const int chunk = blockIdx.y;
    const int b = W * 32 + n;

    const int t0 = (NGT * chunk) / NCH;
    const int t1 = (NGT * (chunk + 1)) / NCH;
    const int nt = t1 - t0;

    stage_sh(gv, lds, t0, nt);

    const half8 bf = make_bfrag(f4, b, kh);

    // combine pass-1 partials for this lane's b (ascending chunks, first-max)
    float bvv = -INFINITY; int zi = 0;
#pragma unroll
    for (int cc = 0; cc < NCH; ++cc) {
        float vv = P1v[(size_t)cc * NB + b];
        int   ii = P1i[(size_t)cc * NB + b];
        merge_vg(bvv, zi, vv, ii);
    }
    half8 df = {0, 0, 0, 0, 0, 0, 0, 0};
    if (kh == 1) {                           // z_b at k=9,10,11 -> j=1..3
        df[1] = (_Float16)gv[3 * zi + 0];
        df[2] = (_Float16)gv[3 * zi + 1];
        df[3] = (_Float16)gv[3 * zi + 2];
    }
    __syncthreads();

    float bv[16]; int bt[16];
#pragma unroll
    for (int r = 0; r < 16; ++r) { bv[r] = -INFINITY; bt[r] = 0; }

    const floatx16 zero16 = {0.f,0.f,0.f,0.f, 0.f,0.f,0.f,0.f, 0.f,0.f,0.f,0.f, 0.f,0.f,0.f,0.f};
    const float ninf = -INFINITY;
    const float lim = 0.2f;
    const half8* lp = &lds[n * 2 + kh];

    half8 af = *lp; lp += 64;
#pragma unroll 2
    for (int t = 0; t < nt - 1; ++t) {
        half8 afn = *lp; lp += 64;
        floatx16 cs = __builtin_amdgcn_mfma_f32_32x32x16_f16(af, bf, zero16, 0, 0, 0);
        floatx16 cd = __builtin_amdgcn_mfma_f32_32x32x16_f16(af, df, zero16, 0, 0, 0);
        int tv = t;
#pragma unroll
        for (int r = 0; r < 16; ++r) {
            float cr = cs[r], dr = cd[r], sm;
            asm("v_cmp_gt_f32 vcc, %7, |%3|\n\t"
                "v_cndmask_b32 %4, %5, %2, vcc\n\t"
                "v_cmp_gt_f32 vcc, %4, %0\n\t"
                "v_cndmask_b32 %1, %1, %6, vcc\n\t"
                "v_max_f32 %0, %0, %4"
                : "+v"(bv[r]), "+v"(bt[r]), "+v"(cr), "+v"(dr), "=&v"(sm)
                : "v"(ninf), "v"(tv), "s"(lim)
                : "vcc");
        }
        af = afn;
    }
    {
        floatx16 cs = __builtin_amdgcn_mfma_f32_32x32x16_f16(af, bf, zero16, 0, 0, 0);
        floatx16 cd = __builtin_amdgcn_mfma_f32_32x32x16_f16(af, df, zero16, 0, 0, 0);
        int tv = nt - 1;
#pragma unroll
        for (int r = 0; r < 16; ++r) {
            float cr = cs[r], dr = cd[r], sm;
            asm("v_cmp_gt_f32 vcc, %7, |%3|\n\t"
                "v_cndmask_b32 %4, %5, %2, vcc\n\t"
                "v_cmp_gt_f32 vcc, %4, %0\n\t"
                "v_cndmask_b32 %1, %1, %6, vcc\n\t"
                "v_max_f32 %0, %0, %4"
                : "+v"(bv[r]), "+v"(bt[r]), "+v"(cr), "+v"(dr), "=&v"(sm)
                : "v"(ninf), "v"(tv), "s"(lim)
                : "vcc");
        }
    }
    float v = bv[0]; int g = ((t0 + bt[0]) << 5) + ROWMAP(0, kh);
#pragma unroll
    for (int r = 1; r < 16; ++r)
        merge_vg(v, g, bv[r], ((t0 + bt[r]) << 5) + ROWMAP(r, kh));
    merge_vg(v, g, __shfl_xor(v, 32), __shfl_xor(g, 32));
    if (kh == 0) {
        P2v[(size_t)chunk * NB + b] = v;
        P2i[(size_t)chunk * NB + b] = g;
    }

    // ---- last-block-per-b-group finalize ----
    __threadfence();                         // release our partial stores (all threads)
    __syncthreads();
    if (threadIdx.x == 0) s_ticket = atomicAdd(&cnt[blockIdx.x], 1);
    __syncthreads();
    if (s_ticket != NCH - 1) return;
    __threadfence();                         // acquire other blocks' partials

    if (threadIdx.x >= 128) return;
    const int fb = blockIdx.x * 128 + threadIdx.x;   // this block's 128 b's
    float bz = -INFINITY; int fzi = 0;
#pragma unroll
    for (int cc = 0; cc < NCH; ++cc)
        merge_vg(bz, fzi, P1v[(size_t)cc * NB + fb], P1i[(size_t)cc * NB + fb]);
    float bx = -INFINITY; int fxi = 0;
#pragma unroll
    for (int cc = 0; cc < NCH; ++cc)
        merge_vg(bx, fxi, P2v[(size_t)cc * NB + fb], P2i[(size_t)cc * NB + fb]);

    float zr0 = gv[3 * fzi], zr1 = gv[3 * fzi + 1], zr2 = gv[3 * fzi + 2];
    float xr0 = gv[3 * fxi], xr1 = gv[3 * fxi + 1], xr2 = gv[3 * fxi + 2];
    float zn = sqrtf(zr0 * zr0 + zr1 * zr1 + zr2 * zr2);
    float zd = fmaxf(zn, 1e-12f);
    float z0 = zr0 / zd, z1 = zr1 / zd, z2 = zr2 / zd;
    float pr = xr0 * z0 + xr1 * z1 + xr2 * z2;
    float ux = xr0 - pr * z0, uy = xr1 - pr * z1, uz = xr2 - pr * z2;
    float xn = sqrtf(ux * ux + uy * uy + uz * uz);
    float xd = fmaxf(xn, 1e-12f);
    float x0 = ux / xd, x1 = uy / xd, x2 = uz / xd;
    float y0 = z1 * x2 - z2 * x1;
    float y1 = z2 * x0 - z0 * x2;
    float y2 = z0 * x1 - z1 * x0;
    float m00 = x0, m01 = y0, m02 = z0;
    float m10 = x1, m11 = y1, m12 = z1;
    float m20 = x2, m21 = y2, m22 = z2;
    float q0 = sqrtf(fmaxf(1.0f + m00 + m11 + m22, 0.0f));
    float q1 = sqrtf(fmaxf(1.0f + m00 - m11 - m22, 0.0f));
    float q2 = sqrtf(fmaxf(1.0f - m00 + m11 - m22, 0.0f));
    float q3 = sqrtf(fmaxf(1.0f - m00 - m11 + m22, 0.0f));
    int bq = 0; float qb = q0;
    if (q1 > qb) { qb = q1; bq = 1; }
    if (q2 > qb) { qb = q2; bq = 2; }
    if (q3 > qb) { qb = q3; bq = 3; }
    float dd = 2.0f * fmaxf(qb, 0.1f);
    float wq, qx, qy, qz;
    if (bq == 0)      { wq = q0 * q0;  qx = m21 - m12; qy = m02 - m20; qz = m10 - m01; }
    else if (bq == 1) { wq = m21 - m12; qx = q1 * q1;  qy = m10 + m01; qz = m02 + m20; }
    else if (bq == 2) { wq = m02 - m20; qx = m10 + m01; qy = q2 * q2;  qz = m12 + m21; }
    else              { wq = m10 - m01; qx = m20 + m02; qy = m21 + m12; qz = q3 * q3; }
    out[fb * 4 + 0] = wq / dd;
    out[fb * 4 + 1] = qx / dd;
    out[fb * 4 + 2] = qy / dd;
    out[fb * 4 + 3] = qz / dd;
    out[4 * NB + fb] = f0[fb] * (float)(180.0 / M_PI);
}

extern "C" void kernel_launch(void* const* d_in, const int* in_sizes, int n_in,
                              void* d_out, int out_size, void* d_ws, size_t ws_size,
                              hipStream_t stream) {
    const float* f0 = (const float*)d_in[0];   // [16384, 1]
    const float* f4 = (const float*)d_in[2];   // [16384, 9]
    const float* gv = (const float*)d_in[4];   // [10000, 3]
    float* out = (float*)d_out;
    (void)in_sizes; (void)n_in; (void)out_size; (void)ws_size;

    // ws layout (bytes): P1v 524288 | P1i 524288 | P2v 524288 | P2i 524288 | cnt 512  (~2.1 MB)
    char* W = (char*)d_ws;
    float* P1v = (float*)(W + 0);
    int*   P1i = (int*)(W + 524288);
    float* P2v = (float*)(W + 2 * 524288);
    int*   P2i = (int*)(W + 3 * 524288);
    int*   cnt = (int*)(W + 4 * 524288);

    // 512 b-tiles / 4 waves = 128 blocks x; 8 chunks y = 1024 blocks = 4/CU (40 KiB LDS)
    dim3 grid2(128, NCH);
    k_pass1<<<grid2, 256, 0, stream>>>(f4, gv, P1v, P1i, cnt);
    k_pass2<<<grid2, 256, 0, stream>>>(f0, f4, gv, P1v, P1i, P2v, P2i, cnt, out);
}

// Round 17
// 124.762 us; speedup vs baseline: 1.4954x; 1.4954x over previous
//
#include <hip/hip_runtime.h>
#include <math.h>
#include <stdint.h>

#define NB 16384
#define NG 10000
#define NGT 313           // ceil(NG/32) g-tiles of 32; tail rows NaN-poisoned
#define NGPAD (NGT * 32)  // 10016
#define NCH 8             // g-chunks; chunk c covers tiles [NGT*c/NCH, NGT*(c+1)/NCH)
#define MAXTPC 40         // max tiles per chunk -> exactly 40960 B LDS -> 4 blocks/CU

typedef _Float16 half8 __attribute__((ext_vector_type(8)));
typedef float    floatx16 __attribute__((ext_vector_type(16)));

// C/D row map for 32x32x16: row = (r&3) + 8*(r>>2) + 4*kh  (g_local here)
#define ROWMAP(r, kh) (((r) & 3) + 8 * ((r) >> 2) + 4 * (kh))

// ---------------- Kernel 1: pack per-g K=16 row: [Y4_0..8, x, y, z, 0,0,0,0] f16 ----------------
__global__ __launch_bounds__(256) void k_pack(const float* __restrict__ gv,
                                              half8* __restrict__ y4p) {
    int g = blockIdx.x * 256 + threadIdx.x;
    if (g >= NGPAD) return;
    half8 h0, h1;
    if (g >= NG) {
        const _Float16 qn = (_Float16)__builtin_nanf("");
#pragma unroll
        for (int i = 0; i < 8; ++i) { h0[i] = qn; h1[i] = qn; }
    } else {
        float x = gv[3 * g + 0], y = gv[3 * g + 1], z = gv[3 * g + 2];
        float n = sqrtf(x * x + y * y + z * z);
        float dn = fmaxf(n, 1e-12f);
        float vx = x / dn, vy = y / dn, vz = z / dn;
        float x2 = vx * vx, y2 = vy * vy, z2 = vz * vz;
        const float c_m4 = (float)(0.75 * sqrt(35.0 / M_PI));
        const float c_m3 = (float)(0.75 * sqrt(35.0 / (2.0 * M_PI)));
        const float c_m2 = (float)(0.75 * sqrt(5.0 / M_PI));
        const float c_m1 = (float)(0.75 * sqrt(5.0 / (2.0 * M_PI)));
        const float c_0  = (float)((3.0 / 16.0) * sqrt(1.0 / M_PI));
        const float c_p2 = (float)((3.0 / 8.0) * sqrt(5.0 / M_PI));
        const float c_p4 = (float)((3.0 / 16.0) * sqrt(35.0 / M_PI));
        h0[0] = (_Float16)(c_m4 * vx * vy * (x2 - y2));
        h0[1] = (_Float16)(c_m3 * vy * vz * (3.0f * x2 - y2));
        h0[2] = (_Float16)(c_m2 * vx * vy * (7.0f * z2 - 1.0f));
        h0[3] = (_Float16)(c_m1 * vy * vz * (7.0f * z2 - 3.0f));
        h0[4] = (_Float16)(c_0  * (35.0f * z2 * z2 - 30.0f * z2 + 3.0f));
        h0[5] = (_Float16)(c_m1 * vx * vz * (7.0f * z2 - 3.0f));
        h0[6] = (_Float16)(c_p2 * (x2 - y2) * (7.0f * z2 - 1.0f));
        h0[7] = (_Float16)(c_m3 * vx * vz * (x2 - y2));
        h1 = (half8){0, 0, 0, 0, 0, 0, 0, 0};
        h1[0] = (_Float16)(c_p4 * (x2 * x2 - 6.0f * x2 * y2 + y2 * y2));  // k=8
        h1[1] = (_Float16)x;   // k=9..11: raw grid vec
        h1[2] = (_Float16)y;
        h1[3] = (_Float16)z;
    }
    half8* dst = y4p + (size_t)g * 2;   // 2 x half8 per g row (K=16, 32 B)
    dst[0] = h0; dst[1] = h1;
}

// B-operand frag (f4 for one b column): B[k][col]: col=lane&31, k=(lane>>5)*8+j.
__device__ inline half8 make_bfrag(const float* __restrict__ f4, int b, int kh) {
    half8 a = {0, 0, 0, 0, 0, 0, 0, 0};
    const float* fr = f4 + (size_t)b * 9;
    if (kh == 0) {
#pragma unroll
        for (int j = 0; j < 8; ++j) a[j] = (_Float16)fr[j];
    } else {
        a[0] = (_Float16)fr[8];      // k=8
    }
    return a;
}

// merge (v2,g2) into (v,g) with numpy first-max semantics
__device__ inline void merge_vg(float& v, int& g, float v2, int g2) {
    bool take = (v2 > v) || (v2 == v && g2 < g);
    v = take ? v2 : v;
    g = take ? g2 : g;
}

// ---------------- Kernel 2: pass-1 argmax, LDS-staged, asm select w/ private cond regs ----------------
__global__ __launch_bounds__(256, 2) void k_pass1(const float* __restrict__ f4,
                                                  const half8* __restrict__ y4p,
                                                  float* __restrict__ Pv,
                                                  int* __restrict__ Pi) {
    __shared__ half8 lds[MAXTPC * 64];      // 40960 B exactly -> 4 blocks/CU
    const int lane = threadIdx.x & 63;
    const int w = threadIdx.x >> 6;
    const int W = blockIdx.x * 4 + w;       // b-tile; b = 32W .. 32W+31
    const int n = lane & 31, kh = lane >> 5;
    const int chunk = blockIdx.y;
    const int b = W * 32 + n;

    const int t0 = (NGT * chunk) / NCH;
    const int t1 = (NGT * (chunk + 1)) / NCH;
    const int nt = t1 - t0;

    const half8* gsrc = y4p + (size_t)t0 * 64;
    const int nElem = nt * 64;
    for (int i = threadIdx.x; i < nElem; i += 256) lds[i] = gsrc[i];

    const half8 bf = make_bfrag(f4, b, kh);
    __syncthreads();

    float bv[16]; int bt[16];
#pragma unroll
    for (int r = 0; r < 16; ++r) { bv[r] = -INFINITY; bt[r] = 0; }

    const floatx16 zero16 = {0.f,0.f,0.f,0.f, 0.f,0.f,0.f,0.f, 0.f,0.f,0.f,0.f, 0.f,0.f,0.f,0.f};
    const half8* lp = &lds[n * 2 + kh];

    half8 af = *lp; lp += 64;
#pragma unroll 2
    for (int t = 0; t < nt - 1; ++t) {
        half8 afn = *lp; lp += 64;
        floatx16 c = __builtin_amdgcn_mfma_f32_32x32x16_f16(af, bf, zero16, 0, 0, 0);
        int tv = t;
#pragma unroll
        for (int r = 0; r < 16; ++r) {
            float cr = c[r];
            unsigned long long cc;   // private SGPR-pair cond reg -> chains are independent
            asm("v_cmp_gt_f32 %2, %3, %0\n\t"
                "v_cndmask_b32 %1, %1, %4, %2\n\t"
                "v_max_f32 %0, %0, %3"
                : "+v"(bv[r]), "+v"(bt[r]), "=&s"(cc)
                : "v"(cr), "v"(tv));
        }
        af = afn;
    }
    {
        floatx16 c = __builtin_amdgcn_mfma_f32_32x32x16_f16(af, bf, zero16, 0, 0, 0);
        int tv = nt - 1;
#pragma unroll
        for (int r = 0; r < 16; ++r) {
            float cr = c[r];
            unsigned long long cc;
            asm("v_cmp_gt_f32 %2, %3, %0\n\t"
                "v_cndmask_b32 %1, %1, %4, %2\n\t"
                "v_max_f32 %0, %0, %3"
                : "+v"(bv[r]), "+v"(bt[r]), "=&s"(cc)
                : "v"(cr), "v"(tv));
        }
    }
    // in-lane reduce over the 16 g-rows this lane owns
    float v = bv[0]; int g = ((t0 + bt[0]) << 5) + ROWMAP(0, kh);
#pragma unroll
    for (int r = 1; r < 16; ++r)
        merge_vg(v, g, bv[r], ((t0 + bt[r]) << 5) + ROWMAP(r, kh));
    merge_vg(v, g, __shfl_xor(v, 32), __shfl_xor(g, 32));
    if (kh == 0) {
        Pv[(size_t)chunk * NB + b] = v;
        Pi[(size_t)chunk * NB + b] = g;
    }
}

// ---------------- Kernel 3: pass-2 masked argmax, dual MFMA, asm select w/ private cond regs ----------------
__global__ __launch_bounds__(256, 2) void k_pass2(const float* __restrict__ f4,
                                                  const half8* __restrict__ y4p,
                                                  const float* __restrict__ gv,
                                                  const float* __restrict__ P1v,
                                                  const int* __restrict__ P1i,
                                                  float* __restrict__ P2v,
                                                  int* __restrict__ P2i) {
    __shared__ half8 lds[MAXTPC * 64];
    const int lane = threadIdx.x & 63;
    const int w = threadIdx.x >> 6;
    const int W = blockIdx.x * 4 + w;
    const int n = lane & 31, kh = lane >> 5;
    const int chunk = blockIdx.y;
    const int b = W * 32 + n;

    const int t0 = (NGT * chunk) / NCH;
    const int t1 = (NGT * (chunk + 1)) / NCH;
    const int nt = t1 - t0;

    const half8* gsrc = y4p + (size_t)t0 * 64;
    const int nElem = nt * 64;
    for (int i = threadIdx.x; i < nElem; i += 256) lds[i] = gsrc[i];

    const half8 bf = make_bfrag(f4, b, kh);

    float bvv = -INFINITY; int zi = 0;
#pragma unroll
    for (int cc = 0; cc < NCH; ++cc) {
        float vv = P1v[(size_t)cc * NB + b];
        int   ii = P1i[(size_t)cc * NB + b];
        merge_vg(bvv, zi, vv, ii);
    }
    half8 df = {0, 0, 0, 0, 0, 0, 0, 0};
    if (kh == 1) {                           // z_b at k=9,10,11 -> j=1..3
        df[1] = (_Float16)gv[3 * zi + 0];
        df[2] = (_Float16)gv[3 * zi + 1];
        df[3] = (_Float16)gv[3 * zi + 2];
    }
    __syncthreads();

    float bv[16]; int bt[16];
#pragma unroll
    for (int r = 0; r < 16; ++r) { bv[r] = -INFINITY; bt[r] = 0; }

    const floatx16 zero16 = {0.f,0.f,0.f,0.f, 0.f,0.f,0.f,0.f, 0.f,0.f,0.f,0.f, 0.f,0.f,0.f,0.f};
    const float ninf = -INFINITY;
    const float lim = 0.2f;
    const half8* lp = &lds[n * 2 + kh];

    half8 af = *lp; lp += 64;
#pragma unroll 2
    for (int t = 0; t < nt - 1; ++t) {
        half8 afn = *lp; lp += 64;
        floatx16 cs = __builtin_amdgcn_mfma_f32_32x32x16_f16(af, bf, zero16, 0, 0, 0);
        floatx16 cd = __builtin_amdgcn_mfma_f32_32x32x16_f16(af, df, zero16, 0, 0, 0);
        int tv = t;
#pragma unroll
        for (int r = 0; r < 16; ++r) {
            float cr = cs[r], dr = cd[r], sm;
            unsigned long long cc;
            // %2=cond ; sm = (0.2>|cd|) ? cs : -inf ; bt = (sm>bv) ? t : bt ; bv = max(bv,sm)
            asm("v_cmp_gt_f32 %2, %8, |%4|\n\t"
                "v_cndmask_b32 %5, %6, %3, %2\n\t"
                "v_cmp_gt_f32 %2, %5, %0\n\t"
                "v_cndmask_b32 %1, %1, %7, %2\n\t"
                "v_max_f32 %0, %0, %5"
                : "+v"(bv[r]), "+v"(bt[r]), "=&s"(cc), "+v"(cr), "+v"(dr), "=&v"(sm)
                : "v"(ninf), "v"(tv), "s"(lim));
        }
        af = afn;
    }
    {
        floatx16 cs = __builtin_amdgcn_mfma_f32_32x32x16_f16(af, bf, zero16, 0, 0, 0);
        floatx16 cd = __builtin_amdgcn_mfma_f32_32x32x16_f16(af, df, zero16, 0, 0, 0);
        int tv = nt - 1;
#pragma unroll
        for (int r = 0; r < 16; ++r) {
            float cr = cs[r], dr = cd[r], sm;
            unsigned long long cc;
            asm("v_cmp_gt_f32 %2, %8, |%4|\n\t"
                "v_cndmask_b32 %5, %6, %3, %2\n\t"
                "v_cmp_gt_f32 %2, %5, %0\n\t"
                "v_cndmask_b32 %1, %1, %7, %2\n\t"
                "v_max_f32 %0, %0, %5"
                : "+v"(bv[r]), "+v"(bt[r]), "=&s"(cc), "+v"(cr), "+v"(dr), "=&v"(sm)
                : "v"(ninf), "v"(tv), "s"(lim));
        }
    }
    float v = bv[0]; int g = ((t0 + bt[0]) << 5) + ROWMAP(0, kh);
#pragma unroll
    for (int r = 1; r < 16; ++r)
        merge_vg(v, g, bv[r], ((t0 + bt[r]) << 5) + ROWMAP(r, kh));
    merge_vg(v, g, __shfl_xor(v, 32), __shfl_xor(g, 32));
    if (kh == 0) {
        P2v[(size_t)chunk * NB + b] = v;
        P2i[(size_t)chunk * NB + b] = g;
    }
}

// ---------------- Kernel 4: finalize — combine both passes, frame, quaternion, boundary map ----------------
__global__ __launch_bounds__(256) void k_final(const float* __restrict__ f0,
                                               const float* __restrict__ gv,
                                               const float* __restrict__ P1v,
                                               const int* __restrict__ P1i,
                                               const float* __restrict__ P2v,
                                               const int* __restrict__ P2i,
                                               float* __restrict__ out) {
    int b = blockIdx.x * 256 + threadIdx.x;
    float bz = -INFINITY; int zi = 0;
#pragma unroll
    for (int cc = 0; cc < NCH; ++cc) {
        float v = P1v[(size_t)cc * NB + b];
        int   i = P1i[(size_t)cc * NB + b];
        if (v > bz || (v == bz && i < zi)) { bz = v; zi = i; }
    }
    float bx = -INFINITY; int xi = 0;
#pragma unroll
    for (int cc = 0; cc < NCH; ++cc) {
        float v = P2v[(size_t)cc * NB + b];
        int   i = P2i[(size_t)cc * NB + b];
        if (v > bx || (v == bx && i < xi)) { bx = v; xi = i; }
    }
    float zr0 = gv[3 * zi], zr1 = gv[3 * zi + 1], zr2 = gv[3 * zi + 2];
    float xr0 = gv[3 * xi], xr1 = gv[3 * xi + 1], xr2 = gv[3 * xi + 2];
    float zn = sqrtf(zr0 * zr0 + zr1 * zr1 + zr2 * zr2);
    float zd = fmaxf(zn, 1e-12f);
    float z0 = zr0 / zd, z1 = zr1 / zd, z2 = zr2 / zd;
    float pr = xr0 * z0 + xr1 * z1 + xr2 * z2;
    float ux = xr0 - pr * z0, uy = xr1 - pr * z1, uz = xr2 - pr * z2;
    float xn = sqrtf(ux * ux + uy * uy + uz * uz);
    float xd = fmaxf(xn, 1e-12f);
    float x0 = ux / xd, x1 = uy / xd, x2 = uz / xd;
    float y0 = z1 * x2 - z2 * x1;
    float y1 = z2 * x0 - z0 * x2;
    float y2 = z0 * x1 - z1 * x0;
    float m00 = x0, m01 = y0, m02 = z0;
    float m10 = x1, m11 = y1, m12 = z1;
    float m20 = x2, m21 = y2, m22 = z2;
    float q0 = sqrtf(fmaxf(1.0f + m00 + m11 + m22, 0.0f));
    float q1 = sqrtf(fmaxf(1.0f + m00 - m11 - m22, 0.0f));
    float q2 = sqrtf(fmaxf(1.0f - m00 + m11 - m22, 0.0f));
    float q3 = sqrtf(fmaxf(1.0f - m00 - m11 + m22, 0.0f));
    int bq = 0; float qb = q0;
    if (q1 > qb) { qb = q1; bq = 1; }
    if (q2 > qb) { qb = q2; bq = 2; }
    if (q3 > qb) { qb = q3; bq = 3; }
    float dd = 2.0f * fmaxf(qb, 0.1f);
    float wq, qx, qy, qz;
    if (bq == 0)      { wq = q0 * q0;  qx = m21 - m12; qy = m02 - m20; qz = m10 - m01; }
    else if (bq == 1) { wq = m21 - m12; qx = q1 * q1;  qy = m10 + m01; qz = m02 + m20; }
    else if (bq == 2) { wq = m02 - m20; qx = m10 + m01; qy = q2 * q2;  qz = m12 + m21; }
    else              { wq = m10 - m01; qx = m20 + m02; qy = m21 + m12; qz = q3 * q3; }
    out[b * 4 + 0] = wq / dd;
    out[b * 4 + 1] = qx / dd;
    out[b * 4 + 2] = qy / dd;
    out[b * 4 + 3] = qz / dd;
    out[4 * NB + b] = f0[b] * (float)(180.0 / M_PI);
}

extern "C" void kernel_launch(void* const* d_in, const int* in_sizes, int n_in,
                              void* d_out, int out_size, void* d_ws, size_t ws_size,
                              hipStream_t stream) {
    const float* f0 = (const float*)d_in[0];   // [16384, 1]
    const float* f4 = (const float*)d_in[2];   // [16384, 9]
    const float* gv = (const float*)d_in[4];   // [10000, 3]
    float* out = (float*)d_out;
    (void)in_sizes; (void)n_in; (void)out_size; (void)ws_size;

    // ws layout (bytes): y4pack f16[NGPAD*16] = 320512 (slot 327680) |
    //   P1v f32[NCH*NB] 524288 | P1i 524288 | P2v 524288 | P2i 524288   (~2.42 MB)
    char* W = (char*)d_ws;
    half8* y4p = (half8*)W;
    float* P1v = (float*)(W + 327680);
    int*   P1i = (int*)(W + 327680 + 524288);
    float* P2v = (float*)(W + 327680 + 2 * 524288);
    int*   P2i = (int*)(W + 327680 + 3 * 524288);

    k_pack<<<(NGPAD + 255) / 256, 256, 0, stream>>>(gv, y4p);
    // 512 b-tiles / 4 waves = 128 blocks x; 8 chunks y = 1024 blocks = exactly 4/CU (40 KiB LDS)
    dim3 grid2(128, NCH);
    k_pass1<<<grid2, 256, 0, stream>>>(f4, y4p, P1v, P1i);
    k_pass2<<<grid2, 256, 0, stream>>>(f4, y4p, gv, P1v, P1i, P2v, P2i);
    k_final<<<NB / 256, 256, 0, stream>>>(f0, gv, P1v, P1i, P2v, P2i, out);
}

// Round 19
// 123.667 us; speedup vs baseline: 1.5086x; 1.0089x over previous
//
#include <hip/hip_runtime.h>
#include <math.h>
#include <stdint.h>

#define NB 16384
#define NG 10000
#define NGT 313           // ceil(NG/32) g-tiles of 32; tail rows NaN-poisoned
#define NCH 8             // g-chunks; chunk c covers tiles [NGT*c/NCH, NGT*(c+1)/NCH)
#define MAXTPC 40         // max tiles per chunk -> exactly 40960 B LDS -> 4 blocks/CU

typedef _Float16 half8 __attribute__((ext_vector_type(8)));
typedef float    floatx16 __attribute__((ext_vector_type(16)));

// C/D row map for 32x32x16: row = (r&3) + 8*(r>>2) + 4*kh  (g_local here)
#define ROWMAP(r, kh) (((r) & 3) + 8 * ((r) >> 2) + 4 * (kh))

// ---- stage chunk tiles [t0, t0+nt) into LDS, computing SH rows directly from gv ----
// row g >= NG -> all-NaN (loses every ordered compare and v_max -> never wins argmax)
__device__ inline void stage_sh(const float* __restrict__ gv, half8* lds, int t0, int nt) {
    const int nrows = nt * 32;
    for (int lr = threadIdx.x; lr < nrows; lr += 256) {
        int g = t0 * 32 + lr;
        half8 h0, h1;
        if (g >= NG) {
            const _Float16 qn = (_Float16)__builtin_nanf("");
#pragma unroll
            for (int i = 0; i < 8; ++i) { h0[i] = qn; h1[i] = qn; }
        } else {
            float x = gv[3 * g + 0], y = gv[3 * g + 1], z = gv[3 * g + 2];
            float n = sqrtf(x * x + y * y + z * z);
            float dn = fmaxf(n, 1e-12f);
            float vx = x / dn, vy = y / dn, vz = z / dn;
            float x2 = vx * vx, y2 = vy * vy, z2 = vz * vz;
            const float c_m4 = (float)(0.75 * sqrt(35.0 / M_PI));
            const float c_m3 = (float)(0.75 * sqrt(35.0 / (2.0 * M_PI)));
            const float c_m2 = (float)(0.75 * sqrt(5.0 / M_PI));
            const float c_m1 = (float)(0.75 * sqrt(5.0 / (2.0 * M_PI)));
            const float c_0  = (float)((3.0 / 16.0) * sqrt(1.0 / M_PI));
            const float c_p2 = (float)((3.0 / 8.0) * sqrt(5.0 / M_PI));
            const float c_p4 = (float)((3.0 / 16.0) * sqrt(35.0 / M_PI));
            h0[0] = (_Float16)(c_m4 * vx * vy * (x2 - y2));
            h0[1] = (_Float16)(c_m3 * vy * vz * (3.0f * x2 - y2));
            h0[2] = (_Float16)(c_m2 * vx * vy * (7.0f * z2 - 1.0f));
            h0[3] = (_Float16)(c_m1 * vy * vz * (7.0f * z2 - 3.0f));
            h0[4] = (_Float16)(c_0  * (35.0f * z2 * z2 - 30.0f * z2 + 3.0f));
            h0[5] = (_Float16)(c_m1 * vx * vz * (7.0f * z2 - 3.0f));
            h0[6] = (_Float16)(c_p2 * (x2 - y2) * (7.0f * z2 - 1.0f));
            h0[7] = (_Float16)(c_m3 * vx * vz * (x2 - y2));
            h1 = (half8){0, 0, 0, 0, 0, 0, 0, 0};
            h1[0] = (_Float16)(c_p4 * (x2 * x2 - 6.0f * x2 * y2 + y2 * y2));  // k=8
            h1[1] = (_Float16)x;   // k=9..11: raw grid vec
            h1[2] = (_Float16)y;
            h1[3] = (_Float16)z;
        }
        lds[lr * 2 + 0] = h0;
        lds[lr * 2 + 1] = h1;
    }
}

// B-operand frag (f4 for one b column): B[k][col]: col=lane&31, k=(lane>>5)*8+j.
__device__ inline half8 make_bfrag(const float* __restrict__ f4, int b, int kh) {
    half8 a = {0, 0, 0, 0, 0, 0, 0, 0};
    const float* fr = f4 + (size_t)b * 9;
    if (kh == 0) {
#pragma unroll
        for (int j = 0; j < 8; ++j) a[j] = (_Float16)fr[j];
    } else {
        a[0] = (_Float16)fr[8];      // k=8
    }
    return a;
}

// merge (v2,g2) into (v,g) with numpy first-max semantics
__device__ inline void merge_vg(float& v, int& g, float v2, int g2) {
    bool take = (v2 > v) || (v2 == v && g2 < g);
    v = take ? v2 : v;
    g = take ? g2 : g;
}

// ---------------- Kernel 1: pass-1 argmax, SH staged in-kernel, asm select ----------------
__global__ __launch_bounds__(256, 2) void k_pass1(const float* __restrict__ f4,
                                                  const float* __restrict__ gv,
                                                  float* __restrict__ Pv,
                                                  int* __restrict__ Pi) {
    __shared__ half8 lds[MAXTPC * 64];      // 40960 B exactly -> 4 blocks/CU
    const int lane = threadIdx.x & 63;
    const int w = threadIdx.x >> 6;
    const int W = blockIdx.x * 4 + w;       // b-tile; b = 32W .. 32W+31
    const int n = lane & 31, kh = lane >> 5;
    const int chunk = blockIdx.y;
    const int b = W * 32 + n;

    const int t0 = (NGT * chunk) / NCH;
    const int t1 = (NGT * (chunk + 1)) / NCH;
    const int nt = t1 - t0;

    stage_sh(gv, lds, t0, nt);
    const half8 bf = make_bfrag(f4, b, kh);
    __syncthreads();

    float bv[16]; int bt[16];
#pragma unroll
    for (int r = 0; r < 16; ++r) { bv[r] = -INFINITY; bt[r] = 0; }

    const floatx16 zero16 = {0.f,0.f,0.f,0.f, 0.f,0.f,0.f,0.f, 0.f,0.f,0.f,0.f, 0.f,0.f,0.f,0.f};
    const half8* lp = &lds[n * 2 + kh];

    half8 af = *lp; lp += 64;
#pragma unroll 2
    for (int t = 0; t < nt - 1; ++t) {
        half8 afn = *lp; lp += 64;
        floatx16 c = __builtin_amdgcn_mfma_f32_32x32x16_f16(af, bf, zero16, 0, 0, 0);
        int tv = t;
#pragma unroll
        for (int r = 0; r < 16; ++r) {
            float cr = c[r];
            unsigned long long cc;   // private SGPR-pair cond reg -> chains independent
            asm("v_cmp_gt_f32 %2, %3, %0\n\t"
                "v_cndmask_b32 %1, %1, %4, %2\n\t"
                "v_max_f32 %0, %0, %3"
                : "+v"(bv[r]), "+v"(bt[r]), "=&s"(cc)
                : "v"(cr), "v"(tv));
        }
        af = afn;
    }
    {
        floatx16 c = __builtin_amdgcn_mfma_f32_32x32x16_f16(af, bf, zero16, 0, 0, 0);
        int tv = nt - 1;
#pragma unroll
        for (int r = 0; r < 16; ++r) {
            float cr = c[r];
            unsigned long long cc;
            asm("v_cmp_gt_f32 %2, %3, %0\n\t"
                "v_cndmask_b32 %1, %1, %4, %2\n\t"
                "v_max_f32 %0, %0, %3"
                : "+v"(bv[r]), "+v"(bt[r]), "=&s"(cc)
                : "v"(cr), "v"(tv));
        }
    }
    float v = bv[0]; int g = ((t0 + bt[0]) << 5) + ROWMAP(0, kh);
#pragma unroll
    for (int r = 1; r < 16; ++r)
        merge_vg(v, g, bv[r], ((t0 + bt[r]) << 5) + ROWMAP(r, kh));
    merge_vg(v, g, __shfl_xor(v, 32), __shfl_xor(g, 32));
    if (kh == 0) {
        Pv[(size_t)chunk * NB + b] = v;
        Pi[(size_t)chunk * NB + b] = g;
    }
}

// ---------------- Kernel 2: pass-2 masked argmax, dual MFMA, SH staged in-kernel ----------------
__global__ __launch_bounds__(256, 2) void k_pass2(const float* __restrict__ f4,
                                                  const float* __restrict__ gv,
                                                  const float* __restrict__ P1v,
                                                  const int* __restrict__ P1i,
                                                  float* __restrict__ P2v,
                                                  int* __restrict__ P2i) {
    __shared__ half8 lds[MAXTPC * 64];
    const int lane = threadIdx.x & 63;
    const int w = threadIdx.x >> 6;
    const int W = blockIdx.x * 4 + w;
    const int n = lane & 31, kh = lane >> 5;
    const int chunk = blockIdx.y;
    const int b = W * 32 + n;

    const int t0 = (NGT * chunk) / NCH;
    const int t1 = (NGT * (chunk + 1)) / NCH;
    const int nt = t1 - t0;

    stage_sh(gv, lds, t0, nt);

    const half8 bf = make_bfrag(f4, b, kh);

    float bvv = -INFINITY; int zi = 0;
#pragma unroll
    for (int cc = 0; cc < NCH; ++cc) {
        float vv = P1v[(size_t)cc * NB + b];
        int   ii = P1i[(size_t)cc * NB + b];
        merge_vg(bvv, zi, vv, ii);
    }
    half8 df = {0, 0, 0, 0, 0, 0, 0, 0};
    if (kh == 1) {                           // z_b at k=9,10,11 -> j=1..3
        df[1] = (_Float16)gv[3 * zi + 0];
        df[2] = (_Float16)gv[3 * zi + 1];
        df[3] = (_Float16)gv[3 * zi + 2];
    }
    __syncthreads();

    float bv[16]; int bt[16];
#pragma unroll
    for (int r = 0; r < 16; ++r) { bv[r] = -INFINITY; bt[r] = 0; }

    const floatx16 zero16 = {0.f,0.f,0.f,0.f, 0.f,0.f,0.f,0.f, 0.f,0.f,0.f,0.f, 0.f,0.f,0.f,0.f};
    const float ninf = -INFINITY;
    const float lim = 0.2f;
    const half8* lp = &lds[n * 2 + kh];

    half8 af = *lp; lp += 64;
#pragma unroll 2
    for (int t = 0; t < nt - 1; ++t) {
        half8 afn = *lp; lp += 64;
        floatx16 cs = __builtin_amdgcn_mfma_f32_32x32x16_f16(af, bf, zero16, 0, 0, 0);
        floatx16 cd = __builtin_amdgcn_mfma_f32_32x32x16_f16(af, df, zero16, 0, 0, 0);
        int tv = t;
#pragma unroll
        for (int r = 0; r < 16; ++r) {
            float cr = cs[r], dr = cd[r], sm;
            unsigned long long cc;
            // %2=cond ; sm = (0.2>|cd|) ? cs : -inf ; bt = (sm>bv) ? t : bt ; bv = max(bv,sm)
            asm("v_cmp_gt_f32 %2, %8, |%4|\n\t"
                "v_cndmask_b32 %5, %6, %3, %2\n\t"
                "v_cmp_gt_f32 %2, %5, %0\n\t"
                "v_cndmask_b32 %1, %1, %7, %2\n\t"
                "v_max_f32 %0, %0, %5"
                : "+v"(bv[r]), "+v"(bt[r]), "=&s"(cc), "+v"(cr), "+v"(dr), "=&v"(sm)
                : "v"(ninf), "v"(tv), "s"(lim));
        }
        af = afn;
    }
    {
        floatx16 cs = __builtin_amdgcn_mfma_f32_32x32x16_f16(af, bf, zero16, 0, 0, 0);
        floatx16 cd = __builtin_amdgcn_mfma_f32_32x32x16_f16(af, df, zero16, 0, 0, 0);
        int tv = nt - 1;
#pragma unroll
        for (int r = 0; r < 16; ++r) {
            float cr = cs[r], dr = cd[r], sm;
            unsigned long long cc;
            asm("v_cmp_gt_f32 %2, %8, |%4|\n\t"
                "v_cndmask_b32 %5, %6, %3, %2\n\t"
                "v_cmp_gt_f32 %2, %5, %0\n\t"
                "v_cndmask_b32 %1, %1, %7, %2\n\t"
                "v_max_f32 %0, %0, %5"
                : "+v"(bv[r]), "+v"(bt[r]), "=&s"(cc), "+v"(cr), "+v"(dr), "=&v"(sm)
                : "v"(ninf), "v"(tv), "s"(lim));
        }
    }
    float v = bv[0]; int g = ((t0 + bt[0]) << 5) + ROWMAP(0, kh);
#pragma unroll
    for (int r = 1; r < 16; ++r)
        merge_vg(v, g, bv[r], ((t0 + bt[r]) << 5) + ROWMAP(r, kh));
    merge_vg(v, g, __shfl_xor(v, 32), __shfl_xor(g, 32));
    if (kh == 0) {
        P2v[(size_t)chunk * NB + b] = v;
        P2i[(size_t)chunk * NB + b] = g;
    }
}

// ---------------- Kernel 3: finalize — combine both passes, frame, quaternion, boundary map ----------------
__global__ __launch_bounds__(256) void k_final(const float* __restrict__ f0,
                                               const float* __restrict__ gv,
                                               const float* __restrict__ P1v,
                                               const int* __restrict__ P1i,
                                               const float* __restrict__ P2v,
                                               const int* __restrict__ P2i,
                                               float* __restrict__ out) {
    int b = blockIdx.x * 256 + threadIdx.x;
    float bz = -INFINITY; int zi = 0;
#pragma unroll
    for (int cc = 0; cc < NCH; ++cc) {
        float v = P1v[(size_t)cc * NB + b];
        int   i = P1i[(size_t)cc * NB + b];
        if (v > bz || (v == bz && i < zi)) { bz = v; zi = i; }
    }
    float bx = -INFINITY; int xi = 0;
#pragma unroll
    for (int cc = 0; cc < NCH; ++cc) {
        float v = P2v[(size_t)cc * NB + b];
        int   i = P2i[(size_t)cc * NB + b];
        if (v > bx || (v == bx && i < xi)) { bx = v; xi = i; }
    }
    float zr0 = gv[3 * zi], zr1 = gv[3 * zi + 1], zr2 = gv[3 * zi + 2];
    float xr0 = gv[3 * xi], xr1 = gv[3 * xi + 1], xr2 = gv[3 * xi + 2];
    float zn = sqrtf(zr0 * zr0 + zr1 * zr1 + zr2 * zr2);
    float zd = fmaxf(zn, 1e-12f);
    float z0 = zr0 / zd, z1 = zr1 / zd, z2 = zr2 / zd;
    float pr = xr0 * z0 + xr1 * z1 + xr2 * z2;
    float ux = xr0 - pr * z0, uy = xr1 - pr * z1, uz = xr2 - pr * z2;
    float xn = sqrtf(ux * ux + uy * uy + uz * uz);
    float xd = fmaxf(xn, 1e-12f);
    float x0 = ux / xd, x1 = uy / xd, x2 = uz / xd;
    float y0 = z1 * x2 - z2 * x1;
    float y1 = z2 * x0 - z0 * x2;
    float y2 = z0 * x1 - z1 * x0;
    float m00 = x0, m01 = y0, m02 = z0;
    float m10 = x1, m11 = y1, m12 = z1;
    float m20 = x2, m21 = y2, m22 = z2;
    float q0 = sqrtf(fmaxf(1.0f + m00 + m11 + m22, 0.0f));
    float q1 = sqrtf(fmaxf(1.0f + m00 - m11 - m22, 0.0f));
    float q2 = sqrtf(fmaxf(1.0f - m00 + m11 - m22, 0.0f));
    float q3 = sqrtf(fmaxf(1.0f - m00 - m11 + m22, 0.0f));
    int bq = 0; float qb = q0;
    if (q1 > qb) { qb = q1; bq = 1; }
    if (q2 > qb) { qb = q2; bq = 2; }
    if (q3 > qb) { qb = q3; bq = 3; }
    float dd = 2.0f * fmaxf(qb, 0.1f);
    float wq, qx, qy, qz;
    if (bq == 0)      { wq = q0 * q0;  qx = m21 - m12; qy = m02 - m20; qz = m10 - m01; }
    else if (bq == 1) { wq = m21 - m12; qx = q1 * q1;  qy = m10 + m01; qz = m02 + m20; }
    else if (bq == 2) { wq = m02 - m20; qx = m10 + m01; qy = q2 * q2;  qz = m12 + m21; }
    else              { wq = m10 - m01; qx = m20 + m02; qy = m21 + m12; qz = q3 * q3; }
    out[b * 4 + 0] = wq / dd;
    out[b * 4 + 1] = qx / dd;
    out[b * 4 + 2] = qy / dd;
    out[b * 4 + 3] = qz / dd;
    out[4 * NB + b] = f0[b] * (float)(180.0 / M_PI);
}

extern "C" void kernel_launch(void* const* d_in, const int* in_sizes, int n_in,
                              void* d_out, int out_size, void* d_ws, size_t ws_size,
                              hipStream_t stream) {
    const float* f0 = (const float*)d_in[0];   // [16384, 1]
    const float* f4 = (const float*)d_in[2];   // [16384, 9]
    const float* gv = (const float*)d_in[4];   // [10000, 3]
    float* out = (float*)d_out;
    (void)in_sizes; (void)n_in; (void)out_size; (void)ws_size;

    // ws layout (bytes): P1v 524288 | P1i 524288 | P2v 524288 | P2i 524288  (~2.1 MB)
    char* W = (char*)d_ws;
    float* P1v = (float*)(W + 0);
    int*   P1i = (int*)(W + 524288);
    float* P2v = (float*)(W + 2 * 524288);
    int*   P2i = (int*)(W + 3 * 524288);

    // 512 b-tiles / 4 waves = 128 blocks x; 8 chunks y = 1024 blocks = exactly 4/CU (40960 B LDS)
    dim3 grid2(128, NCH);
    k_pass1<<<grid2, 256, 0, stream>>>(f4, gv, P1v, P1i);
    k_pass2<<<grid2, 256, 0, stream>>>(f4, gv, P1v, P1i, P2v, P2i);
    k_final<<<NB / 256, 256, 0, stream>>>(f0, gv, P1v, P1i, P2v, P2i, out);
}